// Round 3
// baseline (1224.675 us; speedup 1.0000x reference)
//
#include <hip/hip_runtime.h>
#include <stdint.h>

typedef unsigned short u16;
typedef __bf16 bf16x8 __attribute__((ext_vector_type(8)));
typedef float f32x4 __attribute__((ext_vector_type(4)));

#define DEVI __device__ __forceinline__

static constexpr int DIM = 768;
static constexpr int SEQL = 3136;   // 56*56
static constexpr int MROWS = 25088; // 8*3136
static constexpr int HEADS = 12;
static constexpr int HD = 64;
static constexpr int NW = 196;      // tokens per window
static constexpr float QSCALE = 0.125f; // 64^-0.5

DEVI float b2f(u16 u) { union { unsigned i; float f; } v; v.i = ((unsigned)u) << 16; return v.f; }
DEVI u16 f2b(float f) { union { float f; unsigned u; } v; v.f = f; return (u16)((v.u + 0x7FFFu + ((v.u >> 16) & 1u)) >> 16); }

DEVI void gl_lds16(const void* g, void* l) {
  __builtin_amdgcn_global_load_lds((const __attribute__((address_space(1))) void*)g,
                                   (__attribute__((address_space(3))) void*)l, 16, 0, 0);
}

// 8B-aligned global bf16x8 load (two dwordx2)
DEVI bf16x8 ldg_b8(const u16* p) {
  union { uint4 u; bf16x8 v; } r;
  const uint2* p2 = (const uint2*)p;
  uint2 lo = p2[0], hi = p2[1];
  r.u.x = lo.x; r.u.y = lo.y; r.u.z = hi.x; r.u.w = hi.y;
  return r.v;
}

// ---------------- weight transpose + f32->bf16 convert: W[K][N] -> Wt[N][K] ---------------
__global__ __launch_bounds__(256) void transpose_cvt(const float* __restrict__ in,
                                                     u16* __restrict__ out, int K, int N) {
  __shared__ float t[32][33];
  int n0 = blockIdx.x * 32, k0 = blockIdx.y * 32;
  int tx = threadIdx.x, ty = threadIdx.y; // (32,8)
  #pragma unroll
  for (int i = ty; i < 32; i += 8) t[i][tx] = in[(size_t)(k0 + i) * N + n0 + tx];
  __syncthreads();
  #pragma unroll
  for (int i = ty; i < 32; i += 8) out[(size_t)(n0 + i) * K + k0 + tx] = f2b(t[tx][i]);
}

// ---------------- layernorm (768 cols); REMAP=window-partition the output row ---------------
template<bool REMAP>
__global__ __launch_bounds__(256) void ln_kernel(const float* __restrict__ xin,
                                                 const float* __restrict__ g,
                                                 const float* __restrict__ bb,
                                                 u16* __restrict__ outw) {
  __shared__ float red[8];
  const int r = blockIdx.x;
  const int tid = threadIdx.x;
  const float* xr = xin + (size_t)r * DIM;
  float v0 = xr[tid], v1 = xr[tid + 256], v2 = xr[tid + 512];
  float s1 = v0 + v1 + v2;
  float s2 = v0 * v0 + v1 * v1 + v2 * v2;
  #pragma unroll
  for (int o = 32; o > 0; o >>= 1) { s1 += __shfl_down(s1, o); s2 += __shfl_down(s2, o); }
  const int l = tid & 63, w = tid >> 6;
  if (l == 0) { red[w] = s1; red[w + 4] = s2; }
  __syncthreads();
  float ts = red[0] + red[1] + red[2] + red[3];
  float tss = red[4] + red[5] + red[6] + red[7];
  float mean = ts * (1.f / 768.f);
  float var = tss * (1.f / 768.f) - mean * mean;
  float rstd = rsqrtf(var + 1e-5f);
  size_t orow;
  if constexpr (REMAP) {
    int b = r / SEQL, s = r % SEQL;
    int h = s / 56, ww = s % 56;
    orow = (size_t)(b * 16 + (h / 14) * 4 + (ww / 14)) * NW + (h % 14) * 14 + (ww % 14);
  } else {
    orow = (size_t)r;
  }
  u16* orp = outw + orow * DIM;
  orp[tid]       = f2b((v0 - mean) * rstd * g[tid]       + bb[tid]);
  orp[tid + 256] = f2b((v1 - mean) * rstd * g[tid + 256] + bb[tid + 256]);
  orp[tid + 512] = f2b((v2 - mean) * rstd * g[tid + 512] + bb[tid + 512]);
}

// ---------------- GEMM: A[M][K](bf16) x Bt[N][K](bf16) -> epilogue, 128x128x32 tiles ---------
struct Epi {
  const float* bias;
  const float* x;   // proj: residual input (f32)
  float* outf;      // proj/fc2: f32 out (d_out)
  u16* q; u16* k; u16* v; // qkv outputs (v is transposed: [wh][64][196])
  u16* o16;         // fc1 out
};

template<int K, int N, int EPI>
__global__ __launch_bounds__(256)
void gemm_ep(const u16* __restrict__ A, const u16* __restrict__ Bt, Epi ep) {
  __shared__ __align__(16) u16 sA[128 * 32];
  __shared__ __align__(16) u16 sB[128 * 32];
  const int tid = threadIdx.x;
  const int l = tid & 63, w = tid >> 6;
  const int lr = l & 15, lg = l >> 4;
  const int nbn = N / 128;
  const int bm = blockIdx.x / nbn, bn = blockIdx.x % nbn;
  const int wm = (w >> 1) * 64, wn = (w & 1) * 64;

  const u16* Ab = A + (size_t)bm * 128 * K;
  const u16* Bb = Bt + (size_t)bn * 128 * K;

  f32x4 zero4 = {0.f, 0.f, 0.f, 0.f};
  f32x4 acc[4][4];
  #pragma unroll
  for (int i = 0; i < 4; ++i)
    #pragma unroll
    for (int j = 0; j < 4; ++j) acc[i][j] = zero4;

  const int so = w * 1024 + l * 16;      // lane byte offset in 4KB issue
  const int r0 = so >> 6;                // row (64B per row of 32 bf16)
  const int c0 = (so & 63) >> 1;         // col element

  for (int k0 = 0; k0 < K; k0 += 32) {
    __syncthreads();
    gl_lds16(Ab + (size_t)r0 * K + k0 + c0,        (char*)sA + (w * 1024));
    gl_lds16(Ab + (size_t)(r0 + 64) * K + k0 + c0, (char*)sA + (4096 + w * 1024));
    gl_lds16(Bb + (size_t)r0 * K + k0 + c0,        (char*)sB + (w * 1024));
    gl_lds16(Bb + (size_t)(r0 + 64) * K + k0 + c0, (char*)sB + (4096 + w * 1024));
    __syncthreads();
    bf16x8 af[4], bfv[4];
    #pragma unroll
    for (int mf = 0; mf < 4; ++mf)
      af[mf] = *(const bf16x8*)(sA + (wm + mf * 16 + lr) * 32 + lg * 8);
    #pragma unroll
    for (int nf = 0; nf < 4; ++nf)
      bfv[nf] = *(const bf16x8*)(sB + (wn + nf * 16 + lr) * 32 + lg * 8);
    #pragma unroll
    for (int mf = 0; mf < 4; ++mf)
      #pragma unroll
      for (int nf = 0; nf < 4; ++nf)
        acc[mf][nf] = __builtin_amdgcn_mfma_f32_16x16x32_bf16(af[mf], bfv[nf], acc[mf][nf], 0, 0, 0);
  }

  const int mrow0 = bm * 128 + wm + lg * 4;
  const int ncol0 = bn * 128 + wn + lr;
  #pragma unroll
  for (int mf = 0; mf < 4; ++mf) {
    #pragma unroll
    for (int nf = 0; nf < 4; ++nf) {
      #pragma unroll
      for (int e = 0; e < 4; ++e) {
        int r = mrow0 + mf * 16 + e;
        int c = ncol0 + nf * 16;
        float v = acc[mf][nf][e] + ep.bias[c];
        if constexpr (EPI == 0) { // qkv scatter; v goes out transposed [wh][d][pos]
          int which = c / DIM;
          int hdc = c - which * DIM;
          int head = hdc >> 6, d = hdc & 63;
          int win = r / NW, pos = r - win * NW;
          size_t wh = (size_t)win * HEADS + head;
          if (which == 0)      ep.q[(wh * NW + pos) * HD + d] = f2b(v * QSCALE);
          else if (which == 1) ep.k[(wh * NW + pos) * HD + d] = f2b(v);
          else                 ep.v[(wh * HD + d) * NW + pos] = f2b(v);
        } else if constexpr (EPI == 1) { // proj: window-reverse + residual -> f32 d_out
          int win = r / NW, pos = r - win * NW;
          int b = win >> 4, wi = win & 15;
          int hh = (wi >> 2) * 14 + pos / 14;
          int ww = (wi & 3) * 14 + pos % 14;
          size_t orow = (size_t)b * SEQL + hh * 56 + ww;
          ep.outf[orow * DIM + c] = ep.x[orow * DIM + c] + v;
        } else if constexpr (EPI == 2) { // fc1: exact GELU -> bf16
          float gg = 0.5f * v * (1.f + erff(v * 0.70710678118654752f));
          ep.o16[(size_t)r * N + c] = f2b(gg);
        } else { // fc2: residual with d_out (x1), write f32
          size_t idx = (size_t)r * N + c;
          ep.outf[idx] = ep.outf[idx] + v;
        }
      }
    }
  }
}

// ---------------- fused window attention: one wave per (chunk, win*head) ---------------
// grid (13, 1536), block 64. Q,K read from global (L2-hot); V pre-transposed in global.
__global__ __launch_bounds__(64)
void attn_kernel(const u16* __restrict__ qbuf, const u16* __restrict__ kbuf,
                 const u16* __restrict__ vt, const float* __restrict__ rph,
                 const float* __restrict__ rpw, u16* __restrict__ abuf) {
  __shared__ __align__(16) u16 sP[16 * 232];   // P chunk, padded stride 232 (464B)
  __shared__ float sRB[16 * 28];               // rel bias for this chunk's 16 rows

  const int l = threadIdx.x;
  const int lr = l & 15, lg = l >> 4;
  const int chunk = blockIdx.x;                // 0..12
  const int wh = blockIdx.y;                   // win*12 + head
  const int win = wh / HEADS, head = wh - win * HEADS;

  const u16* Qw = qbuf + (size_t)wh * NW * HD;
  const u16* Kw = kbuf + (size_t)wh * NW * HD;
  const u16* Vt = vt + (size_t)wh * HD * NW;   // [64][196]

  // rel-pos bias for the 16 rows of this chunk: sRB[row][t], t<14: h-term, t>=14: w-term
  #pragma unroll
  for (int t7 = 0; t7 < 7; ++t7) {
    int idx = t7 * 64 + l;                     // 0..447 = 16*28
    int row = idx / 28, t = idx - row * 28;
    int gi = chunk * 16 + row;
    float a = 0.f;
    if (gi < 196) {
      int ih = gi / 14, iw = gi - ih * 14;
      const float* rp = (t < 14) ? (rph + (size_t)(ih - t + 13) * HD)
                                 : (rpw + (size_t)(iw - (t - 14) + 13) * HD);
      const uint4* qrow4 = (const uint4*)(Qw + (size_t)gi * HD);
      #pragma unroll
      for (int cb = 0; cb < 8; ++cb) {
        uint4 qv = qrow4[cb];
        const u16* qs = (const u16*)&qv;
        #pragma unroll
        for (int j = 0; j < 8; ++j) a += b2f(qs[j]) * rp[cb * 8 + j];
      }
    }
    sRB[idx] = a;
  }
  __syncthreads();

  // ---- QK^T for 16 rows x 208 cols ----
  int qrow = chunk * 16 + lr; if (qrow > 195) qrow = 195;
  bf16x8 aq0 = *(const bf16x8*)(Qw + (size_t)qrow * HD + lg * 8);
  bf16x8 aq1 = *(const bf16x8*)(Qw + (size_t)qrow * HD + 32 + lg * 8);

  f32x4 zero4 = {0.f, 0.f, 0.f, 0.f};
  f32x4 accs[13];
  #pragma unroll
  for (int nf = 0; nf < 13; ++nf) {
    int krow = nf * 16 + lr; if (krow > 195) krow = 195;
    bf16x8 b0 = *(const bf16x8*)(Kw + (size_t)krow * HD + lg * 8);
    bf16x8 b1 = *(const bf16x8*)(Kw + (size_t)krow * HD + 32 + lg * 8);
    f32x4 c = zero4;
    c = __builtin_amdgcn_mfma_f32_16x16x32_bf16(aq0, b0, c, 0, 0, 0);
    c = __builtin_amdgcn_mfma_f32_16x16x32_bf16(aq1, b1, c, 0, 0, 0);
    accs[nf] = c;
  }

  // ---- bias + mask + softmax (rows = lg*4+e local) ----
  float mrow[4] = {-3e38f, -3e38f, -3e38f, -3e38f};
  #pragma unroll
  for (int nf = 0; nf < 13; ++nf) {
    int j = nf * 16 + lr;                      // col 0..207
    int jh = (j * 9363) >> 17;                 // j/14
    int jw = j - jh * 14;
    #pragma unroll
    for (int e = 0; e < 4; ++e) {
      int ic = lg * 4 + e;                     // local row
      float s = accs[nf][e] + sRB[ic * 28 + jh] + sRB[ic * 28 + 14 + jw];
      if (nf == 12 && lr >= 4) s = -1e30f;     // mask cols >= 196
      accs[nf][e] = s;
      mrow[e] = fmaxf(mrow[e], s);
    }
  }
  #pragma unroll
  for (int e = 0; e < 4; ++e) {
    float v = mrow[e];
    v = fmaxf(v, __shfl_xor(v, 1)); v = fmaxf(v, __shfl_xor(v, 2));
    v = fmaxf(v, __shfl_xor(v, 4)); v = fmaxf(v, __shfl_xor(v, 8));
    mrow[e] = v;
  }
  float ssum[4] = {0.f, 0.f, 0.f, 0.f};
  #pragma unroll
  for (int nf = 0; nf < 13; ++nf)
    #pragma unroll
    for (int e = 0; e < 4; ++e) {
      float p = __expf(accs[nf][e] - mrow[e]);
      accs[nf][e] = p;
      ssum[e] += p;
    }
  #pragma unroll
  for (int e = 0; e < 4; ++e) {
    float v = ssum[e];
    v += __shfl_xor(v, 1); v += __shfl_xor(v, 2);
    v += __shfl_xor(v, 4); v += __shfl_xor(v, 8);
    ssum[e] = 1.f / v;
  }
  #pragma unroll
  for (int nf = 0; nf < 13; ++nf)
    #pragma unroll
    for (int e = 0; e < 4; ++e)
      sP[(lg * 4 + e) * 232 + nf * 16 + lr] = f2b(accs[nf][e] * ssum[e]);
  #pragma unroll
  for (int e = 0; e < 4; ++e) sP[(lg * 4 + e) * 232 + 208 + lr] = 0; // zero cols 208..223
  __syncthreads();

  // ---- PV: out(16x64) = P(16x224) @ V^T rows (global) ----
  f32x4 acco[4];
  #pragma unroll
  for (int nf = 0; nf < 4; ++nf) acco[nf] = zero4;
  #pragma unroll
  for (int ks = 0; ks < 7; ++ks) {
    bf16x8 ap = *(const bf16x8*)(sP + lr * 232 + ks * 32 + lg * 8);
    #pragma unroll
    for (int nf = 0; nf < 4; ++nf) {
      bf16x8 bv = ldg_b8(Vt + (size_t)(nf * 16 + lr) * NW + ks * 32 + lg * 8);
      acco[nf] = __builtin_amdgcn_mfma_f32_16x16x32_bf16(ap, bv, acco[nf], 0, 0, 0);
    }
  }
  u16* ob = abuf + (size_t)win * NW * DIM + head * HD;
  #pragma unroll
  for (int nf = 0; nf < 4; ++nf)
    #pragma unroll
    for (int e = 0; e < 4; ++e) {
      int row = chunk * 16 + lg * 4 + e;
      if (row < 196) ob[(size_t)row * DIM + nf * 16 + lr] = f2b(acco[nf][e]);
    }
}

// ---------------- host launch ---------------
extern "C" void kernel_launch(void* const* d_in, const int* in_sizes, int n_in,
                              void* d_out, int out_size, void* d_ws, size_t ws_size,
                              hipStream_t stream) {
  (void)in_sizes; (void)n_in; (void)out_size; (void)ws_size;
  const float* x    = (const float*)d_in[0];
  const float* ln1s = (const float*)d_in[1];
  const float* ln1b = (const float*)d_in[2];
  const float* qkvw = (const float*)d_in[3];
  const float* qkvb = (const float*)d_in[4];
  const float* rph  = (const float*)d_in[5];
  const float* rpw  = (const float*)d_in[6];
  const float* pjw  = (const float*)d_in[7];
  const float* pjb  = (const float*)d_in[8];
  const float* ln2s = (const float*)d_in[9];
  const float* ln2b = (const float*)d_in[10];
  const float* f1w  = (const float*)d_in[11];
  const float* f1b  = (const float*)d_in[12];
  const float* f2w  = (const float*)d_in[13];
  const float* f2b_ = (const float*)d_in[14];
  float* out = (float*)d_out;

  // ws layout (bytes): [weightsT 14,155,776][xw 38,535,168][q 38.5M][k 38.5M][vT 38.5M][h2 38.5M]
  char* ws = (char*)d_ws;
  u16* qkvwT = (u16*)ws;              // [2304][768]
  u16* projwT = qkvwT + 1769472;      // [768][768]
  u16* fc1wT  = qkvwT + 2359296;      // [3072][768]
  u16* fc2wT  = qkvwT + 4718592;      // [768][3072]
  u16* xw   = (u16*)(ws + 14155776);  // [25088][768]
  u16* qbuf = (u16*)(ws + 52690944);  // [1536][196][64]
  u16* kbuf = qbuf + 19267584;
  u16* vtb  = kbuf + 19267584;        // [1536][64][196]
  u16* h2   = (u16*)(ws + 168296448); // [25088][768]
  u16* abuf = xw;                     // alias (xw dead after qkv gemm)
  u16* h1   = xw;                     // [25088][3072] spans xw+q+k+vT regions (all dead)

  dim3 tb(32, 8);
  transpose_cvt<<<dim3(2304 / 32, 768 / 32), tb, 0, stream>>>(qkvw, qkvwT, 768, 2304);
  transpose_cvt<<<dim3(768 / 32, 768 / 32),  tb, 0, stream>>>(pjw, projwT, 768, 768);
  transpose_cvt<<<dim3(3072 / 32, 768 / 32), tb, 0, stream>>>(f1w, fc1wT, 768, 3072);
  transpose_cvt<<<dim3(768 / 32, 3072 / 32), tb, 0, stream>>>(f2w, fc2wT, 3072, 768);

  ln_kernel<true><<<MROWS, 256, 0, stream>>>(x, ln1s, ln1b, xw);

  { Epi e{}; e.bias = qkvb; e.q = qbuf; e.k = kbuf; e.v = vtb;
    gemm_ep<768, 2304, 0><<<196 * 18, 256, 0, stream>>>(xw, qkvwT, e); }

  attn_kernel<<<dim3(13, 1536), 64, 0, stream>>>(qbuf, kbuf, vtb, rph, rpw, abuf);

  { Epi e{}; e.bias = pjb; e.x = x; e.outf = out;
    gemm_ep<768, 768, 1><<<196 * 6, 256, 0, stream>>>(abuf, projwT, e); }

  ln_kernel<false><<<MROWS, 256, 0, stream>>>(out, ln2s, ln2b, h2);

  { Epi e{}; e.bias = f1b; e.o16 = h1;
    gemm_ep<768, 3072, 2><<<196 * 24, 256, 0, stream>>>(h2, fc1wT, e); }

  { Epi e{}; e.bias = f2b_; e.outf = out;
    gemm_ep<3072, 768, 3><<<196 * 6, 256, 0, stream>>>(h1, fc2wT, e); }
}

// Round 4
// 1202.901 us; speedup vs baseline: 1.0181x; 1.0181x over previous
//
#include <hip/hip_runtime.h>
#include <stdint.h>

typedef unsigned short u16;
typedef __bf16 bf16x8 __attribute__((ext_vector_type(8)));
typedef float f32x4 __attribute__((ext_vector_type(4)));

#define DEVI __device__ __forceinline__

static constexpr int DIM = 768;
static constexpr int SEQL = 3136;   // 56*56
static constexpr int MROWS = 25088; // 8*3136
static constexpr int HEADS = 12;
static constexpr int HD = 64;
static constexpr int NW = 196;      // tokens per window
static constexpr float QSCALE = 0.125f; // 64^-0.5
static constexpr int ATTN_SMEM = 130048; // sQ 28672 + sK 28672 + sVt 32768 + sP 32768 + sRB 7168

DEVI float b2f(u16 u) { union { unsigned i; float f; } v; v.i = ((unsigned)u) << 16; return v.f; }
DEVI u16 f2b(float f) { union { float f; unsigned u; } v; v.f = f; return (u16)((v.u + 0x7FFFu + ((v.u >> 16) & 1u)) >> 16); }

DEVI void gl_lds16(const void* g, void* l) {
  __builtin_amdgcn_global_load_lds((const __attribute__((address_space(1))) void*)g,
                                   (__attribute__((address_space(3))) void*)l, 16, 0, 0);
}

// ---------------- weight transpose + f32->bf16 convert: W[K][N] -> Wt[N][K] ---------------
__global__ __launch_bounds__(256) void transpose_cvt(const float* __restrict__ in,
                                                     u16* __restrict__ out, int K, int N) {
  __shared__ float t[32][33];
  int n0 = blockIdx.x * 32, k0 = blockIdx.y * 32;
  int tx = threadIdx.x, ty = threadIdx.y; // (32,8)
  #pragma unroll
  for (int i = ty; i < 32; i += 8) t[i][tx] = in[(size_t)(k0 + i) * N + n0 + tx];
  __syncthreads();
  #pragma unroll
  for (int i = ty; i < 32; i += 8) out[(size_t)(n0 + i) * K + k0 + tx] = f2b(t[tx][i]);
}

// ---------------- layernorm (768 cols); REMAP=window-partition the output row ---------------
template<bool REMAP>
__global__ __launch_bounds__(256) void ln_kernel(const float* __restrict__ xin,
                                                 const float* __restrict__ g,
                                                 const float* __restrict__ bb,
                                                 u16* __restrict__ outw) {
  __shared__ float red[8];
  const int r = blockIdx.x;
  const int tid = threadIdx.x;
  const float* xr = xin + (size_t)r * DIM;
  float v0 = xr[tid], v1 = xr[tid + 256], v2 = xr[tid + 512];
  float s1 = v0 + v1 + v2;
  float s2 = v0 * v0 + v1 * v1 + v2 * v2;
  #pragma unroll
  for (int o = 32; o > 0; o >>= 1) { s1 += __shfl_down(s1, o); s2 += __shfl_down(s2, o); }
  const int l = tid & 63, w = tid >> 6;
  if (l == 0) { red[w] = s1; red[w + 4] = s2; }
  __syncthreads();
  float ts = red[0] + red[1] + red[2] + red[3];
  float tss = red[4] + red[5] + red[6] + red[7];
  float mean = ts * (1.f / 768.f);
  float var = tss * (1.f / 768.f) - mean * mean;
  float rstd = rsqrtf(var + 1e-5f);
  size_t orow;
  if constexpr (REMAP) {
    int b = r / SEQL, s = r % SEQL;
    int h = s / 56, ww = s % 56;
    orow = (size_t)(b * 16 + (h / 14) * 4 + (ww / 14)) * NW + (h % 14) * 14 + (ww % 14);
  } else {
    orow = (size_t)r;
  }
  u16* orp = outw + orow * DIM;
  orp[tid]       = f2b((v0 - mean) * rstd * g[tid]       + bb[tid]);
  orp[tid + 256] = f2b((v1 - mean) * rstd * g[tid + 256] + bb[tid + 256]);
  orp[tid + 512] = f2b((v2 - mean) * rstd * g[tid + 512] + bb[tid + 512]);
}

// ---------------- GEMM: A[M][K](bf16) x Bt[N][K](bf16) -> epilogue, 128x128x32 tiles ---------
struct Epi {
  const float* bias;
  const float* x;   // proj: residual input (f32)
  float* outf;      // proj/fc2: f32 out (d_out)
  u16* q; u16* k; u16* v; // qkv outputs (v is transposed: [wh][64][196])
  u16* o16;         // fc1 out
};

template<int K, int N, int EPI>
__global__ __launch_bounds__(256)
void gemm_ep(const u16* __restrict__ A, const u16* __restrict__ Bt, Epi ep) {
  __shared__ __align__(16) u16 sA[128 * 32];
  __shared__ __align__(16) u16 sB[128 * 32];
  const int tid = threadIdx.x;
  const int l = tid & 63, w = tid >> 6;
  const int lr = l & 15, lg = l >> 4;
  const int nbn = N / 128;
  const int bm = blockIdx.x / nbn, bn = blockIdx.x % nbn;
  const int wm = (w >> 1) * 64, wn = (w & 1) * 64;

  const u16* Ab = A + (size_t)bm * 128 * K;
  const u16* Bb = Bt + (size_t)bn * 128 * K;

  f32x4 zero4 = {0.f, 0.f, 0.f, 0.f};
  f32x4 acc[4][4];
  #pragma unroll
  for (int i = 0; i < 4; ++i)
    #pragma unroll
    for (int j = 0; j < 4; ++j) acc[i][j] = zero4;

  const int so = w * 1024 + l * 16;      // lane byte offset in 4KB issue
  const int r0 = so >> 6;                // row (64B per row of 32 bf16)
  const int c0 = (so & 63) >> 1;         // col element

  for (int k0 = 0; k0 < K; k0 += 32) {
    __syncthreads();
    gl_lds16(Ab + (size_t)r0 * K + k0 + c0,        (char*)sA + (w * 1024));
    gl_lds16(Ab + (size_t)(r0 + 64) * K + k0 + c0, (char*)sA + (4096 + w * 1024));
    gl_lds16(Bb + (size_t)r0 * K + k0 + c0,        (char*)sB + (w * 1024));
    gl_lds16(Bb + (size_t)(r0 + 64) * K + k0 + c0, (char*)sB + (4096 + w * 1024));
    __syncthreads();
    bf16x8 af[4], bfv[4];
    #pragma unroll
    for (int mf = 0; mf < 4; ++mf)
      af[mf] = *(const bf16x8*)(sA + (wm + mf * 16 + lr) * 32 + lg * 8);
    #pragma unroll
    for (int nf = 0; nf < 4; ++nf)
      bfv[nf] = *(const bf16x8*)(sB + (wn + nf * 16 + lr) * 32 + lg * 8);
    #pragma unroll
    for (int mf = 0; mf < 4; ++mf)
      #pragma unroll
      for (int nf = 0; nf < 4; ++nf)
        acc[mf][nf] = __builtin_amdgcn_mfma_f32_16x16x32_bf16(af[mf], bfv[nf], acc[mf][nf], 0, 0, 0);
  }

  const int mrow0 = bm * 128 + wm + lg * 4;
  const int ncol0 = bn * 128 + wn + lr;
  #pragma unroll
  for (int mf = 0; mf < 4; ++mf) {
    #pragma unroll
    for (int nf = 0; nf < 4; ++nf) {
      #pragma unroll
      for (int e = 0; e < 4; ++e) {
        int r = mrow0 + mf * 16 + e;
        int c = ncol0 + nf * 16;
        float v = acc[mf][nf][e] + ep.bias[c];
        if constexpr (EPI == 0) { // qkv scatter; v goes out transposed [wh][d][pos]
          int which = c / DIM;
          int hdc = c - which * DIM;
          int head = hdc >> 6, d = hdc & 63;
          int win = r / NW, pos = r - win * NW;
          size_t wh = (size_t)win * HEADS + head;
          if (which == 0)      ep.q[(wh * NW + pos) * HD + d] = f2b(v * QSCALE);
          else if (which == 1) ep.k[(wh * NW + pos) * HD + d] = f2b(v);
          else                 ep.v[(wh * HD + d) * NW + pos] = f2b(v);
        } else if constexpr (EPI == 1) { // proj: window-reverse + residual -> f32 d_out
          int win = r / NW, pos = r - win * NW;
          int b = win >> 4, wi = win & 15;
          int hh = (wi >> 2) * 14 + pos / 14;
          int ww = (wi & 3) * 14 + pos % 14;
          size_t orow = (size_t)b * SEQL + hh * 56 + ww;
          ep.outf[orow * DIM + c] = ep.x[orow * DIM + c] + v;
        } else if constexpr (EPI == 2) { // fc1: exact GELU -> bf16
          float gg = 0.5f * v * (1.f + erff(v * 0.70710678118654752f));
          ep.o16[(size_t)r * N + c] = f2b(gg);
        } else { // fc2: residual with d_out (x1), write f32
          size_t idx = (size_t)r * N + c;
          ep.outf[idx] = ep.outf[idx] + v;
        }
      }
    }
  }
}

// ---------------- fused window attention: one 4-wave block per (win*head) ---------------
// grid 1536, block 256. Q/K/Vt staged to LDS once (XOR-swizzled via pre-swizzled source),
// 13 16-row chunks split across the 4 waves (4/3/3/3). One barrier total.
__global__ __launch_bounds__(256, 1)
void attn_kernel(const u16* __restrict__ qbuf, const u16* __restrict__ kbuf,
                 const u16* __restrict__ vt, const float* __restrict__ rph,
                 const float* __restrict__ rpw, u16* __restrict__ abuf) {
  extern __shared__ __align__(16) char smem[];
  u16* sQ  = (u16*)smem;                 // [224][64] elems, 16B-slot s -> s^(row&7)
  u16* sK  = (u16*)(smem + 28672);       // [224][64] same swizzle
  u16* sVt = (u16*)(smem + 57344);       // [64][256] elems, slot s -> s^(row&7)
  u16* sP  = (u16*)(smem + 90112);       // [4][16][256] elems, col ^= (row&7)<<3
  float* sRB = (float*)(smem + 122880);  // [4][16][28]

  const int tid = threadIdx.x;
  const int l = tid & 63, w = tid >> 6;
  const int lr = l & 15, lg = l >> 4;
  const int wh = blockIdx.x;             // win*12 + head
  const int win = wh / HEADS, head = wh - win * HEADS;

  const u16* Qg = qbuf + (size_t)wh * (NW * HD);
  const u16* Kg = kbuf + (size_t)wh * (NW * HD);
  const u16* Vg = vt + (size_t)wh * (HD * NW);   // [64][196]

  // ---- stage Q,K: rows of 128B = 8 slots of 16B; physical slot p holds logical p^(row&7).
  // Source address pre-swizzled so LDS dest stays linear (global_load_lds requirement).
  for (int t = tid; t < 1792; t += 256) {        // 1792*16B = 28672B (rows 196..223 garbage)
    int r8 = t >> 3, c8 = t & 7;
    int s = (t & ~7) | (c8 ^ (r8 & 7));
    if (s >= 1568) s &= 1023;                    // clamp into real data (finite bf16)
    gl_lds16(Qg + s * 8, (char*)sQ + t * 16);
    gl_lds16(Kg + s * 8, (char*)sK + t * 16);
  }
  // ---- stage Vt: 64 rows, 32 slots/row (512B stride; cols 196..255 garbage, killed by P=0)
  for (int t = tid; t < 2048; t += 256) {
    int row = t >> 5, cp = t & 31;
    int cl = cp ^ (row & 7);
    gl_lds16(Vg + row * 196 + cl * 8, (char*)sVt + t * 16);
  }
  __syncthreads();

  f32x4 zero4 = {0.f, 0.f, 0.f, 0.f};
  u16* myP = sP + w * (16 * 256);
  float* rb = sRB + w * (16 * 28);

  for (int c = 0; c < 4; ++c) {
    const int chunk = w + 4 * c;                 // wave w handles chunks w, w+4, w+8, w+12
    if (chunk > 12) break;

    // ---- rel-pos bias for this chunk's 16 rows: rb[row][t], t<14: h-term, else w-term
    #pragma unroll
    for (int t7 = 0; t7 < 7; ++t7) {
      int idx = t7 * 64 + l;                     // 0..447 = 16*28
      int row = idx / 28, t = idx - row * 28;
      int gi = chunk * 16 + row;
      float a = 0.f;
      if (gi < 196) {
        int ih = gi / 14, iw = gi - ih * 14;
        const float* rp = (t < 14) ? (rph + (size_t)(ih - t + 13) * HD)
                                   : (rpw + (size_t)(iw - (t - 14) + 13) * HD);
        int qsw = gi & 7;
        #pragma unroll
        for (int cb = 0; cb < 8; ++cb) {
          uint4 qv = *(const uint4*)(sQ + gi * 64 + ((cb ^ qsw) << 3));
          const u16* qs = (const u16*)&qv;
          #pragma unroll
          for (int j = 0; j < 8; ++j) a += b2f(qs[j]) * rp[cb * 8 + j];
        }
      }
      rb[idx] = a;
    }

    // ---- QK^T: 16 rows x 208 cols from LDS (swizzled reads) ----
    int qrow = chunk * 16 + lr; if (qrow > 195) qrow = 195;
    int qsw = (qrow & 7) << 3;
    bf16x8 aq0 = *(const bf16x8*)(sQ + qrow * 64 + ((lg * 8) ^ qsw));
    bf16x8 aq1 = *(const bf16x8*)(sQ + qrow * 64 + ((32 + lg * 8) ^ qsw));

    f32x4 accs[13];
    #pragma unroll
    for (int nf = 0; nf < 13; ++nf) {
      int krow = nf * 16 + lr;                   // rows 196..207 garbage -> masked below
      int ksw = (krow & 7) << 3;
      bf16x8 b0 = *(const bf16x8*)(sK + krow * 64 + ((lg * 8) ^ ksw));
      bf16x8 b1 = *(const bf16x8*)(sK + krow * 64 + ((32 + lg * 8) ^ ksw));
      f32x4 cc = zero4;
      cc = __builtin_amdgcn_mfma_f32_16x16x32_bf16(aq0, b0, cc, 0, 0, 0);
      cc = __builtin_amdgcn_mfma_f32_16x16x32_bf16(aq1, b1, cc, 0, 0, 0);
      accs[nf] = cc;
    }

    // ---- bias + mask + softmax (rows = lg*4+e local) ----
    float mrow[4] = {-3e38f, -3e38f, -3e38f, -3e38f};
    #pragma unroll
    for (int nf = 0; nf < 13; ++nf) {
      int j = nf * 16 + lr;                      // col 0..207
      int jh = (j * 9363) >> 17;                 // j/14
      int jw = j - jh * 14;
      #pragma unroll
      for (int e = 0; e < 4; ++e) {
        int ic = lg * 4 + e;
        float s = accs[nf][e] + rb[ic * 28 + jh] + rb[ic * 28 + 14 + jw];
        if (nf == 12 && lr >= 4) s = -1e30f;     // mask cols >= 196
        accs[nf][e] = s;
        mrow[e] = fmaxf(mrow[e], s);
      }
    }
    #pragma unroll
    for (int e = 0; e < 4; ++e) {
      float v = mrow[e];
      v = fmaxf(v, __shfl_xor(v, 1)); v = fmaxf(v, __shfl_xor(v, 2));
      v = fmaxf(v, __shfl_xor(v, 4)); v = fmaxf(v, __shfl_xor(v, 8));
      mrow[e] = v;
    }
    float ssum[4] = {0.f, 0.f, 0.f, 0.f};
    #pragma unroll
    for (int nf = 0; nf < 13; ++nf)
      #pragma unroll
      for (int e = 0; e < 4; ++e) {
        float p = __expf(accs[nf][e] - mrow[e]);
        accs[nf][e] = p;
        ssum[e] += p;
      }
    #pragma unroll
    for (int e = 0; e < 4; ++e) {
      float v = ssum[e];
      v += __shfl_xor(v, 1); v += __shfl_xor(v, 2);
      v += __shfl_xor(v, 4); v += __shfl_xor(v, 8);
      ssum[e] = 1.f / v;
    }
    #pragma unroll
    for (int nf = 0; nf < 13; ++nf)
      #pragma unroll
      for (int e = 0; e < 4; ++e) {
        int prow = lg * 4 + e;
        myP[prow * 256 + ((nf * 16 + lr) ^ ((prow & 7) << 3))] = f2b(accs[nf][e] * ssum[e]);
      }
    #pragma unroll
    for (int e = 0; e < 4; ++e) {
      int prow = lg * 4 + e;
      myP[prow * 256 + ((208 + lr) ^ ((prow & 7) << 3))] = 0; // zero cols 208..223
    }

    // ---- PV: out(16x64) = P(16x224) @ Vt rows (all LDS, swizzled) ----
    f32x4 acco[4];
    #pragma unroll
    for (int nf = 0; nf < 4; ++nf) acco[nf] = zero4;
    int asw = (lr & 7) << 3;
    #pragma unroll
    for (int ks = 0; ks < 7; ++ks) {
      bf16x8 ap = *(const bf16x8*)(myP + lr * 256 + ((ks * 32 + lg * 8) ^ asw));
      #pragma unroll
      for (int nf = 0; nf < 4; ++nf) {
        int vrow = nf * 16 + lr;
        int vsw = (vrow & 7) << 3;
        bf16x8 bv = *(const bf16x8*)(sVt + vrow * 256 + ((ks * 32 + lg * 8) ^ vsw));
        acco[nf] = __builtin_amdgcn_mfma_f32_16x16x32_bf16(ap, bv, acco[nf], 0, 0, 0);
      }
    }
    u16* ob = abuf + (size_t)win * NW * DIM + head * HD;
    #pragma unroll
    for (int nf = 0; nf < 4; ++nf)
      #pragma unroll
      for (int e = 0; e < 4; ++e) {
        int row = chunk * 16 + lg * 4 + e;
        if (row < 196) ob[(size_t)row * DIM + nf * 16 + lr] = f2b(acco[nf][e]);
      }
  }
}

// ---------------- host launch ---------------
extern "C" void kernel_launch(void* const* d_in, const int* in_sizes, int n_in,
                              void* d_out, int out_size, void* d_ws, size_t ws_size,
                              hipStream_t stream) {
  (void)in_sizes; (void)n_in; (void)out_size; (void)ws_size;
  const float* x    = (const float*)d_in[0];
  const float* ln1s = (const float*)d_in[1];
  const float* ln1b = (const float*)d_in[2];
  const float* qkvw = (const float*)d_in[3];
  const float* qkvb = (const float*)d_in[4];
  const float* rph  = (const float*)d_in[5];
  const float* rpw  = (const float*)d_in[6];
  const float* pjw  = (const float*)d_in[7];
  const float* pjb  = (const float*)d_in[8];
  const float* ln2s = (const float*)d_in[9];
  const float* ln2b = (const float*)d_in[10];
  const float* f1w  = (const float*)d_in[11];
  const float* f1b  = (const float*)d_in[12];
  const float* f2w  = (const float*)d_in[13];
  const float* f2b_ = (const float*)d_in[14];
  float* out = (float*)d_out;

  // ws layout (bytes): [weightsT 14,155,776][xw 38,535,168][q 38.5M][k 38.5M][vT 38.5M][h2 38.5M]
  char* ws = (char*)d_ws;
  u16* qkvwT = (u16*)ws;              // [2304][768]
  u16* projwT = qkvwT + 1769472;      // [768][768]
  u16* fc1wT  = qkvwT + 2359296;      // [3072][768]
  u16* fc2wT  = qkvwT + 4718592;      // [768][3072]
  u16* xw   = (u16*)(ws + 14155776);  // [25088][768]
  u16* qbuf = (u16*)(ws + 52690944);  // [1536][196][64]
  u16* kbuf = qbuf + 19267584;
  u16* vtb  = kbuf + 19267584;        // [1536][64][196]
  u16* h2   = (u16*)(ws + 168296448); // [25088][768]
  u16* abuf = xw;                     // alias (xw dead after qkv gemm)
  u16* h1   = xw;                     // [25088][3072] spans xw+q+k+vT regions (all dead)

  (void)hipFuncSetAttribute((const void*)attn_kernel,
                            hipFuncAttributeMaxDynamicSharedMemorySize, ATTN_SMEM);

  dim3 tb(32, 8);
  transpose_cvt<<<dim3(2304 / 32, 768 / 32), tb, 0, stream>>>(qkvw, qkvwT, 768, 2304);
  transpose_cvt<<<dim3(768 / 32, 768 / 32),  tb, 0, stream>>>(pjw, projwT, 768, 768);
  transpose_cvt<<<dim3(3072 / 32, 768 / 32), tb, 0, stream>>>(f1w, fc1wT, 768, 3072);
  transpose_cvt<<<dim3(768 / 32, 3072 / 32), tb, 0, stream>>>(f2w, fc2wT, 3072, 768);

  ln_kernel<true><<<MROWS, 256, 0, stream>>>(x, ln1s, ln1b, xw);

  { Epi e{}; e.bias = qkvb; e.q = qbuf; e.k = kbuf; e.v = vtb;
    gemm_ep<768, 2304, 0><<<196 * 18, 256, 0, stream>>>(xw, qkvwT, e); }

  attn_kernel<<<1536, 256, ATTN_SMEM, stream>>>(qbuf, kbuf, vtb, rph, rpw, abuf);

  { Epi e{}; e.bias = pjb; e.x = x; e.outf = out;
    gemm_ep<768, 768, 1><<<196 * 6, 256, 0, stream>>>(abuf, projwT, e); }

  ln_kernel<false><<<MROWS, 256, 0, stream>>>(out, ln2s, ln2b, h2);

  { Epi e{}; e.bias = f1b; e.o16 = h1;
    gemm_ep<768, 3072, 2><<<196 * 24, 256, 0, stream>>>(h2, fc1wT, e); }

  { Epi e{}; e.bias = f2b_; e.outf = out;
    gemm_ep<3072, 768, 3><<<196 * 6, 256, 0, stream>>>(h1, fc2wT, e); }
}

// Round 5
// 912.913 us; speedup vs baseline: 1.3415x; 1.3177x over previous
//
#include <hip/hip_runtime.h>
#include <stdint.h>

typedef unsigned short u16;
typedef __bf16 bf16x8 __attribute__((ext_vector_type(8)));
typedef float f32x4 __attribute__((ext_vector_type(4)));

#define DEVI __device__ __forceinline__

static constexpr int DIM = 768;
static constexpr int SEQL = 3136;   // 56*56
static constexpr int MROWS = 25088; // 8*3136
static constexpr int HEADS = 12;
static constexpr int HD = 64;
static constexpr int NW = 196;      // tokens per window
static constexpr float QSCALE = 0.125f; // 64^-0.5
// LDS: sK [208][64]u16 26624 + sP 4*[16][232]u16 29696 + sT 4*[16][64]f32 16384
static constexpr int ATTN_SMEM = 72704;

DEVI float b2f(u16 u) { union { unsigned i; float f; } v; v.i = ((unsigned)u) << 16; return v.f; }
DEVI u16 f2b(float f) { union { float f; unsigned u; } v; v.f = f; return (u16)((v.u + 0x7FFFu + ((v.u >> 16) & 1u)) >> 16); }

DEVI void gl_lds16(const void* g, void* l) {
  __builtin_amdgcn_global_load_lds((const __attribute__((address_space(1))) void*)g,
                                   (__attribute__((address_space(3))) void*)l, 16, 0, 0);
}

// 8B-aligned global bf16x8 load (two dwordx2)
DEVI bf16x8 ldg_b8(const u16* p) {
  union { uint4 u; bf16x8 v; } r;
  const uint2* p2 = (const uint2*)p;
  uint2 lo = p2[0], hi = p2[1];
  r.u.x = lo.x; r.u.y = lo.y; r.u.z = hi.x; r.u.w = hi.y;
  return r.v;
}

// ---------------- weight transpose + f32->bf16 convert: W[K][N] -> Wt[N][K] ---------------
__global__ __launch_bounds__(256) void transpose_cvt(const float* __restrict__ in,
                                                     u16* __restrict__ out, int K, int N) {
  __shared__ float t[32][33];
  int n0 = blockIdx.x * 32, k0 = blockIdx.y * 32;
  int tx = threadIdx.x, ty = threadIdx.y; // (32,8)
  #pragma unroll
  for (int i = ty; i < 32; i += 8) t[i][tx] = in[(size_t)(k0 + i) * N + n0 + tx];
  __syncthreads();
  #pragma unroll
  for (int i = ty; i < 32; i += 8) out[(size_t)(n0 + i) * K + k0 + tx] = f2b(t[tx][i]);
}

// ---------------- rel-pos tables f32 [27][64] -> bf16 [2][32][64] (rows>=27 zero) --------
__global__ __launch_bounds__(256) void cvt_rpb(const float* __restrict__ rph,
                                               const float* __restrict__ rpw,
                                               u16* __restrict__ rpb) {
  int i = blockIdx.x * 256 + threadIdx.x;  // 0..4095
  int tbl = i >> 11, r = (i >> 6) & 31, c = i & 63;
  float v = (r < 27) ? (tbl ? rpw : rph)[r * 64 + c] : 0.f;
  rpb[i] = f2b(v);
}

// ---------------- layernorm (768 cols); REMAP=window-partition the output row ---------------
template<bool REMAP>
__global__ __launch_bounds__(256) void ln_kernel(const float* __restrict__ xin,
                                                 const float* __restrict__ g,
                                                 const float* __restrict__ bb,
                                                 u16* __restrict__ outw) {
  __shared__ float red[8];
  const int r = blockIdx.x;
  const int tid = threadIdx.x;
  const float* xr = xin + (size_t)r * DIM;
  float v0 = xr[tid], v1 = xr[tid + 256], v2 = xr[tid + 512];
  float s1 = v0 + v1 + v2;
  float s2 = v0 * v0 + v1 * v1 + v2 * v2;
  #pragma unroll
  for (int o = 32; o > 0; o >>= 1) { s1 += __shfl_down(s1, o); s2 += __shfl_down(s2, o); }
  const int l = tid & 63, w = tid >> 6;
  if (l == 0) { red[w] = s1; red[w + 4] = s2; }
  __syncthreads();
  float ts = red[0] + red[1] + red[2] + red[3];
  float tss = red[4] + red[5] + red[6] + red[7];
  float mean = ts * (1.f / 768.f);
  float var = tss * (1.f / 768.f) - mean * mean;
  float rstd = rsqrtf(var + 1e-5f);
  size_t orow;
  if constexpr (REMAP) {
    int b = r / SEQL, s = r % SEQL;
    int h = s / 56, ww = s % 56;
    orow = (size_t)(b * 16 + (h / 14) * 4 + (ww / 14)) * NW + (h % 14) * 14 + (ww % 14);
  } else {
    orow = (size_t)r;
  }
  u16* orp = outw + orow * DIM;
  orp[tid]       = f2b((v0 - mean) * rstd * g[tid]       + bb[tid]);
  orp[tid + 256] = f2b((v1 - mean) * rstd * g[tid + 256] + bb[tid + 256]);
  orp[tid + 512] = f2b((v2 - mean) * rstd * g[tid + 512] + bb[tid + 512]);
}

// ---------------- GEMM: A[M][K](bf16) x Bt[N][K](bf16) -> epilogue, 128x128x32 tiles ---------
struct Epi {
  const float* bias;
  const float* x;   // proj: residual input (f32)
  float* outf;      // proj/fc2: f32 out (d_out)
  u16* q; u16* k; u16* v; // qkv outputs (v is transposed: [wh][64][196])
  u16* o16;         // fc1 out
};

template<int K, int N, int EPI>
__global__ __launch_bounds__(256)
void gemm_ep(const u16* __restrict__ A, const u16* __restrict__ Bt, Epi ep) {
  __shared__ __align__(16) u16 sA[128 * 32];
  __shared__ __align__(16) u16 sB[128 * 32];
  const int tid = threadIdx.x;
  const int l = tid & 63, w = tid >> 6;
  const int lr = l & 15, lg = l >> 4;
  const int nbn = N / 128;
  const int bm = blockIdx.x / nbn, bn = blockIdx.x % nbn;
  const int wm = (w >> 1) * 64, wn = (w & 1) * 64;

  const u16* Ab = A + (size_t)bm * 128 * K;
  const u16* Bb = Bt + (size_t)bn * 128 * K;

  f32x4 zero4 = {0.f, 0.f, 0.f, 0.f};
  f32x4 acc[4][4];
  #pragma unroll
  for (int i = 0; i < 4; ++i)
    #pragma unroll
    for (int j = 0; j < 4; ++j) acc[i][j] = zero4;

  const int so = w * 1024 + l * 16;      // lane byte offset in 4KB issue
  const int r0 = so >> 6;                // row (64B per row of 32 bf16)
  const int c0 = (so & 63) >> 1;         // col element

  for (int k0 = 0; k0 < K; k0 += 32) {
    __syncthreads();
    gl_lds16(Ab + (size_t)r0 * K + k0 + c0,        (char*)sA + (w * 1024));
    gl_lds16(Ab + (size_t)(r0 + 64) * K + k0 + c0, (char*)sA + (4096 + w * 1024));
    gl_lds16(Bb + (size_t)r0 * K + k0 + c0,        (char*)sB + (w * 1024));
    gl_lds16(Bb + (size_t)(r0 + 64) * K + k0 + c0, (char*)sB + (4096 + w * 1024));
    __syncthreads();
    bf16x8 af[4], bfv[4];
    #pragma unroll
    for (int mf = 0; mf < 4; ++mf)
      af[mf] = *(const bf16x8*)(sA + (wm + mf * 16 + lr) * 32 + lg * 8);
    #pragma unroll
    for (int nf = 0; nf < 4; ++nf)
      bfv[nf] = *(const bf16x8*)(sB + (wn + nf * 16 + lr) * 32 + lg * 8);
    #pragma unroll
    for (int mf = 0; mf < 4; ++mf)
      #pragma unroll
      for (int nf = 0; nf < 4; ++nf)
        acc[mf][nf] = __builtin_amdgcn_mfma_f32_16x16x32_bf16(af[mf], bfv[nf], acc[mf][nf], 0, 0, 0);
  }

  const int mrow0 = bm * 128 + wm + lg * 4;
  const int ncol0 = bn * 128 + wn + lr;
  #pragma unroll
  for (int mf = 0; mf < 4; ++mf) {
    #pragma unroll
    for (int nf = 0; nf < 4; ++nf) {
      #pragma unroll
      for (int e = 0; e < 4; ++e) {
        int r = mrow0 + mf * 16 + e;
        int c = ncol0 + nf * 16;
        float v = acc[mf][nf][e] + ep.bias[c];
        if constexpr (EPI == 0) { // qkv scatter; v goes out transposed [wh][d][pos]
          int which = c / DIM;
          int hdc = c - which * DIM;
          int head = hdc >> 6, d = hdc & 63;
          int win = r / NW, pos = r - win * NW;
          size_t wh = (size_t)win * HEADS + head;
          if (which == 0)      ep.q[(wh * NW + pos) * HD + d] = f2b(v * QSCALE);
          else if (which == 1) ep.k[(wh * NW + pos) * HD + d] = f2b(v);
          else                 ep.v[(wh * HD + d) * NW + pos] = f2b(v);
        } else if constexpr (EPI == 1) { // proj: window-reverse + residual -> f32 d_out
          int win = r / NW, pos = r - win * NW;
          int b = win >> 4, wi = win & 15;
          int hh = (wi >> 2) * 14 + pos / 14;
          int ww = (wi & 3) * 14 + pos % 14;
          size_t orow = (size_t)b * SEQL + hh * 56 + ww;
          ep.outf[orow * DIM + c] = ep.x[orow * DIM + c] + v;
        } else if constexpr (EPI == 2) { // fc1: exact GELU -> bf16
          float gg = 0.5f * v * (1.f + erff(v * 0.70710678118654752f));
          ep.o16[(size_t)r * N + c] = f2b(gg);
        } else { // fc2: residual with d_out (x1), write f32
          size_t idx = (size_t)r * N + c;
          ep.outf[idx] = ep.outf[idx] + v;
        }
      }
    }
  }
}

// ---------------- fused window attention v3: one 4-wave block per (win*head) ------------
// K staged in LDS (swizzled); Q, V^T, rel-tables read from global (CU-local reuse).
// Rel-pos bias via MFMA T-tables (T = Q_chunk @ table^T), not scalar dot products.
// LDS 72.7 KB -> 2 blocks/CU (2 waves/SIMD).
__global__ __launch_bounds__(256, 2)
void attn_kernel(const u16* __restrict__ qbuf, const u16* __restrict__ kbuf,
                 const u16* __restrict__ vt, const u16* __restrict__ rpb,
                 u16* __restrict__ abuf) {
  extern __shared__ __align__(16) char smem[];
  u16* sK = (u16*)smem;                  // [208][64], 16B-slot s -> s^(row&7)
  u16* sP = (u16*)(smem + 26624);        // 4 x [16][232]
  float* sT = (float*)(smem + 56320);    // 4 x [16][64]: cols 0..26 h-term, 32..58 w-term

  const int tid = threadIdx.x;
  const int l = tid & 63, w = tid >> 6;
  const int lr = l & 15, lg = l >> 4;
  const int wh = blockIdx.x;             // win*12 + head
  const int win = wh / HEADS, head = wh - win * HEADS;

  const u16* Qg = qbuf + (size_t)wh * (NW * HD);
  const u16* Kg = kbuf + (size_t)wh * (NW * HD);
  const u16* Vg = vt + (size_t)wh * (HD * NW);   // [64][196]

  // ---- stage K: 208 rows of 128B = 8 slots of 16B; slot p holds logical p^(row&7)
  for (int t = tid; t < 1664; t += 256) {
    int r8 = t >> 3, c8 = t & 7;
    int s = (t & ~7) | (c8 ^ (r8 & 7));
    if (s >= 1568) s &= 1023;            // rows 196..207: clamp into real data (masked later)
    gl_lds16(Kg + s * 8, (char*)sK + t * 16);
  }
  __syncthreads();

  f32x4 zero4 = {0.f, 0.f, 0.f, 0.f};
  u16* myP = sP + w * (16 * 232);
  float* myT = sT + w * (16 * 64);

  for (int c = 0; c < 4; ++c) {
    const int chunk = w + 4 * c;                 // wave w -> chunks w, w+4, w+8, w+12
    if (chunk > 12) break;

    // ---- Q fragments for this chunk (16 rows) straight from global
    int qrow = chunk * 16 + lr; if (qrow > 195) qrow = 195;
    bf16x8 aq0 = *(const bf16x8*)(Qg + (size_t)qrow * HD + lg * 8);
    bf16x8 aq1 = *(const bf16x8*)(Qg + (size_t)qrow * HD + 32 + lg * 8);

    // ---- T-tables via MFMA: T_h[i][d] = q_i . rph[d], T_w[i][d] = q_i . rpw[d]
    f32x4 th[2], tw[2];
    #pragma unroll
    for (int nf2 = 0; nf2 < 2; ++nf2) {
      const u16* bh = rpb + (nf2 * 16 + lr) * 64;
      const u16* bw = rpb + 2048 + (nf2 * 16 + lr) * 64;
      f32x4 a = zero4, b = zero4;
      a = __builtin_amdgcn_mfma_f32_16x16x32_bf16(aq0, *(const bf16x8*)(bh + lg * 8), a, 0, 0, 0);
      a = __builtin_amdgcn_mfma_f32_16x16x32_bf16(aq1, *(const bf16x8*)(bh + 32 + lg * 8), a, 0, 0, 0);
      b = __builtin_amdgcn_mfma_f32_16x16x32_bf16(aq0, *(const bf16x8*)(bw + lg * 8), b, 0, 0, 0);
      b = __builtin_amdgcn_mfma_f32_16x16x32_bf16(aq1, *(const bf16x8*)(bw + 32 + lg * 8), b, 0, 0, 0);
      th[nf2] = a; tw[nf2] = b;
    }
    #pragma unroll
    for (int nf2 = 0; nf2 < 2; ++nf2)
      #pragma unroll
      for (int e = 0; e < 4; ++e) {
        myT[(lg * 4 + e) * 64 + nf2 * 16 + lr]      = th[nf2][e];
        myT[(lg * 4 + e) * 64 + 32 + nf2 * 16 + lr] = tw[nf2][e];
      }

    // ---- QK^T: 16 rows x 208 cols from LDS (swizzled reads)
    f32x4 accs[13];
    #pragma unroll
    for (int nf = 0; nf < 13; ++nf) {
      int krow = nf * 16 + lr;                   // rows 196..207 garbage -> masked below
      int ksw = (krow & 7) << 3;
      bf16x8 b0 = *(const bf16x8*)(sK + krow * 64 + ((lg * 8) ^ ksw));
      bf16x8 b1 = *(const bf16x8*)(sK + krow * 64 + ((32 + lg * 8) ^ ksw));
      f32x4 cc = zero4;
      cc = __builtin_amdgcn_mfma_f32_16x16x32_bf16(aq0, b0, cc, 0, 0, 0);
      cc = __builtin_amdgcn_mfma_f32_16x16x32_bf16(aq1, b1, cc, 0, 0, 0);
      accs[nf] = cc;
    }

    // ---- bias (T-table lookups) + mask + softmax (rows = lg*4+e local)
    int ihv[4], iwv[4];
    #pragma unroll
    for (int e = 0; e < 4; ++e) {
      int gi = chunk * 16 + lg * 4 + e;          // up to 207; (x*9363)>>17 valid < 224
      ihv[e] = (gi * 9363) >> 17;
      iwv[e] = gi - ihv[e] * 14;
    }
    float mrow[4] = {-3e38f, -3e38f, -3e38f, -3e38f};
    #pragma unroll
    for (int nf = 0; nf < 13; ++nf) {
      int j = nf * 16 + lr;                      // col 0..207
      int jh = (j * 9363) >> 17;                 // j/14 (14 for masked cols)
      int jw = j - jh * 14;
      #pragma unroll
      for (int e = 0; e < 4; ++e) {
        int ic = lg * 4 + e;
        float s = accs[nf][e]
                + myT[ic * 64 + ((ihv[e] - jh + 13) & 63)]
                + myT[ic * 64 + 32 + (iwv[e] - jw + 13)];
        if (nf == 12 && lr >= 4) s = -1e30f;     // mask cols >= 196
        accs[nf][e] = s;
        mrow[e] = fmaxf(mrow[e], s);
      }
    }
    #pragma unroll
    for (int e = 0; e < 4; ++e) {
      float v = mrow[e];
      v = fmaxf(v, __shfl_xor(v, 1)); v = fmaxf(v, __shfl_xor(v, 2));
      v = fmaxf(v, __shfl_xor(v, 4)); v = fmaxf(v, __shfl_xor(v, 8));
      mrow[e] = v;
    }
    float ssum[4] = {0.f, 0.f, 0.f, 0.f};
    #pragma unroll
    for (int nf = 0; nf < 13; ++nf)
      #pragma unroll
      for (int e = 0; e < 4; ++e) {
        float p = __expf(accs[nf][e] - mrow[e]);
        accs[nf][e] = p;
        ssum[e] += p;
      }
    #pragma unroll
    for (int e = 0; e < 4; ++e) {
      float v = ssum[e];
      v += __shfl_xor(v, 1); v += __shfl_xor(v, 2);
      v += __shfl_xor(v, 4); v += __shfl_xor(v, 8);
      ssum[e] = 1.f / v;
    }
    #pragma unroll
    for (int nf = 0; nf < 13; ++nf)
      #pragma unroll
      for (int e = 0; e < 4; ++e)
        myP[(lg * 4 + e) * 232 + nf * 16 + lr] = f2b(accs[nf][e] * ssum[e]);
    #pragma unroll
    for (int e = 0; e < 4; ++e)
      myP[(lg * 4 + e) * 232 + 208 + lr] = 0;    // zero cols 208..223

    // ---- PV: out(16x64) = P(16x224) @ V^T rows from global (CU-local L1/L2)
    f32x4 acco[4];
    #pragma unroll
    for (int nf = 0; nf < 4; ++nf) acco[nf] = zero4;
    #pragma unroll
    for (int ks = 0; ks < 7; ++ks) {
      bf16x8 ap = *(const bf16x8*)(myP + lr * 232 + ks * 32 + lg * 8);
      #pragma unroll
      for (int nf = 0; nf < 4; ++nf) {
        bf16x8 bv = ldg_b8(Vg + (size_t)(nf * 16 + lr) * NW + ks * 32 + lg * 8);
        acco[nf] = __builtin_amdgcn_mfma_f32_16x16x32_bf16(ap, bv, acco[nf], 0, 0, 0);
      }
    }
    u16* ob = abuf + (size_t)win * NW * DIM + head * HD;
    #pragma unroll
    for (int nf = 0; nf < 4; ++nf)
      #pragma unroll
      for (int e = 0; e < 4; ++e) {
        int row = chunk * 16 + lg * 4 + e;
        if (row < 196) ob[(size_t)row * DIM + nf * 16 + lr] = f2b(acco[nf][e]);
      }
  }
}

// ---------------- host launch ---------------
extern "C" void kernel_launch(void* const* d_in, const int* in_sizes, int n_in,
                              void* d_out, int out_size, void* d_ws, size_t ws_size,
                              hipStream_t stream) {
  (void)in_sizes; (void)n_in; (void)out_size; (void)ws_size;
  const float* x    = (const float*)d_in[0];
  const float* ln1s = (const float*)d_in[1];
  const float* ln1b = (const float*)d_in[2];
  const float* qkvw = (const float*)d_in[3];
  const float* qkvb = (const float*)d_in[4];
  const float* rph  = (const float*)d_in[5];
  const float* rpw  = (const float*)d_in[6];
  const float* pjw  = (const float*)d_in[7];
  const float* pjb  = (const float*)d_in[8];
  const float* ln2s = (const float*)d_in[9];
  const float* ln2b = (const float*)d_in[10];
  const float* f1w  = (const float*)d_in[11];
  const float* f1b  = (const float*)d_in[12];
  const float* f2w  = (const float*)d_in[13];
  const float* f2b_ = (const float*)d_in[14];
  float* out = (float*)d_out;

  // ws layout (bytes): [weightsT 14,155,776][xw 38,535,168][q 38.5M][k 38.5M][vT 38.5M][h2 38.5M]
  char* ws = (char*)d_ws;
  u16* qkvwT = (u16*)ws;              // [2304][768]
  u16* projwT = qkvwT + 1769472;      // [768][768]
  u16* fc1wT  = qkvwT + 2359296;      // [3072][768]
  u16* fc2wT  = qkvwT + 4718592;      // [768][3072]
  u16* xw   = (u16*)(ws + 14155776);  // [25088][768]
  u16* qbuf = (u16*)(ws + 52690944);  // [1536][196][64]
  u16* kbuf = qbuf + 19267584;
  u16* vtb  = kbuf + 19267584;        // [1536][64][196]
  u16* h2   = (u16*)(ws + 168296448); // [25088][768]
  u16* abuf = xw;                     // alias (xw dead after qkv gemm)
  u16* h1   = xw;                     // [25088][3072] spans xw+q+k+vT regions (all dead)
  u16* rpb  = h2;                     // [2][32][64] bf16 tables; h2 written only after attn

  (void)hipFuncSetAttribute((const void*)attn_kernel,
                            hipFuncAttributeMaxDynamicSharedMemorySize, ATTN_SMEM);

  dim3 tb(32, 8);
  transpose_cvt<<<dim3(2304 / 32, 768 / 32), tb, 0, stream>>>(qkvw, qkvwT, 768, 2304);
  transpose_cvt<<<dim3(768 / 32, 768 / 32),  tb, 0, stream>>>(pjw, projwT, 768, 768);
  transpose_cvt<<<dim3(3072 / 32, 768 / 32), tb, 0, stream>>>(f1w, fc1wT, 768, 3072);
  transpose_cvt<<<dim3(768 / 32, 3072 / 32), tb, 0, stream>>>(f2w, fc2wT, 3072, 768);
  cvt_rpb<<<16, 256, 0, stream>>>(rph, rpw, rpb);

  ln_kernel<true><<<MROWS, 256, 0, stream>>>(x, ln1s, ln1b, xw);

  { Epi e{}; e.bias = qkvb; e.q = qbuf; e.k = kbuf; e.v = vtb;
    gemm_ep<768, 2304, 0><<<196 * 18, 256, 0, stream>>>(xw, qkvwT, e); }

  attn_kernel<<<1536, 256, ATTN_SMEM, stream>>>(qbuf, kbuf, vtb, rpb, abuf);

  { Epi e{}; e.bias = pjb; e.x = x; e.outf = out;
    gemm_ep<768, 768, 1><<<196 * 6, 256, 0, stream>>>(abuf, projwT, e); }

  ln_kernel<false><<<MROWS, 256, 0, stream>>>(out, ln2s, ln2b, h2);

  { Epi e{}; e.bias = f1b; e.o16 = h1;
    gemm_ep<768, 3072, 2><<<196 * 24, 256, 0, stream>>>(h2, fc1wT, e); }

  { Epi e{}; e.bias = f2b_; e.outf = out;
    gemm_ep<3072, 768, 3><<<196 * 6, 256, 0, stream>>>(h1, fc2wT, e); }
}